// Round 1
// baseline (1249.935 us; speedup 1.0000x reference)
//
#include <hip/hip_runtime.h>

#define HH 512
#define WW 640
#define TH 8
#define TW 32
#define HR (TH+2)      // 10 h1 rows
#define HC (TW+2)      // 34 h1 cols
#define NPIX (HR*HC)   // 340
#define NTHREADS 256

__launch_bounds__(NTHREADS, 2)
__global__ void fastprop_kernel(const float* __restrict__ depth,
                                const float* __restrict__ img,
                                const float* __restrict__ w1,
                                const float* __restrict__ b1,
                                const float* __restrict__ gamma,
                                const float* __restrict__ beta,
                                const float* __restrict__ rmean,
                                const float* __restrict__ rvar,
                                const float* __restrict__ w2,
                                float* __restrict__ out)
{
    __shared__ float s_h1[32*NPIX];      // 10880 f = 42.5 KB, [oc][p]
    __shared__ float s_w1[16*32*12];     //  6144 f = 24.0 KB, [c][oc][tap pad 12]
    __shared__ float s_w2[32*84];        //  2688 f = 10.5 KB, [oc][k*9+t pad 84]
    __shared__ float s_A[32], s_B[32];

    const int tid = threadIdx.x;

    // ---- stage weights into LDS ----
    for (int i = tid; i < 32*16*9; i += NTHREADS) {
        int oc = i / 144; int rem = i - oc*144; int c = rem / 9; int t = rem - c*9;
        s_w1[(c*32 + oc)*12 + t] = w1[i];
    }
    for (int i = tid; i < 9*32*9; i += NTHREADS) {
        int k = i / 288; int rem = i - k*288; int oc = rem / 9; int t = rem - oc*9;
        s_w2[oc*84 + k*9 + t] = w2[i];
    }
    if (tid < 32) {
        float a = gamma[tid] * rsqrtf(rvar[tid] + 1e-5f);
        s_A[tid] = a;
        s_B[tid] = beta[tid] + (b1[tid] - rmean[tid]) * a;
    }
    __syncthreads();

    const int b   = blockIdx.z;
    const int gy0 = blockIdx.y * TH;
    const int gx0 = blockIdx.x * TW;
    const float* imgb = img + (size_t)b * 16 * HH * WW;

    // ---- phase 2: conv1 + BN + relu into s_h1 (halo tile, zero at image OOB) ----
    for (int p = tid; p < NPIX; p += NTHREADS) {
        int ly = p / HC, lx = p - ly*HC;
        int gy = gy0 + ly - 1, gx = gx0 + lx - 1;
        int off[9]; float msk[9];
        #pragma unroll
        for (int t = 0; t < 9; ++t) {
            int dy = t/3 - 1, dx = t - (t/3)*3 - 1;
            int yy = gy + dy, xx = gx + dx;
            bool v = (yy >= 0 && yy < HH && xx >= 0 && xx < WW);
            int yc = min(max(yy, 0), HH-1), xc = min(max(xx, 0), WW-1);
            off[t] = yc*WW + xc;
            msk[t] = v ? 1.f : 0.f;
        }
        float acc[32];
        #pragma unroll
        for (int oc = 0; oc < 32; ++oc) acc[oc] = 0.f;
        for (int c = 0; c < 16; ++c) {
            const float* ip = imgb + c*HH*WW;
            float v[9];
            #pragma unroll
            for (int t = 0; t < 9; ++t) v[t] = ip[off[t]] * msk[t];
            const float* wp = &s_w1[c*32*12];
            #pragma unroll
            for (int oc = 0; oc < 32; ++oc) {
                #pragma unroll
                for (int t = 0; t < 9; ++t)
                    acc[oc] = fmaf(v[t], wp[oc*12 + t], acc[oc]);
            }
        }
        bool inb = (gy >= 0 && gy < HH && gx >= 0 && gx < WW);
        #pragma unroll
        for (int oc = 0; oc < 32; ++oc) {
            float h = fmaxf(fmaf(acc[oc], s_A[oc], s_B[oc]), 0.f);
            s_h1[oc*NPIX + p] = inb ? h : 0.f;
        }
    }
    __syncthreads();

    // ---- phase 3: conv2 + softmax + depth gather ----
    {
        int ly = tid >> 5, lx = tid & 31;   // 8x32 output tile, 1 px/thread
        float lg[9];
        #pragma unroll
        for (int k = 0; k < 9; ++k) lg[k] = 0.f;
        for (int oc = 0; oc < 32; ++oc) {
            const float* hp = &s_h1[oc*NPIX + ly*HC + lx];
            float hv[9];
            #pragma unroll
            for (int t = 0; t < 9; ++t) hv[t] = hp[(t/3)*HC + (t - (t/3)*3)];
            const float* wp = &s_w2[oc*84];
            #pragma unroll
            for (int k = 0; k < 9; ++k) {
                #pragma unroll
                for (int t = 0; t < 9; ++t)
                    lg[k] = fmaf(hv[t], wp[k*9 + t], lg[k]);
            }
        }
        float mx = lg[0];
        #pragma unroll
        for (int k = 1; k < 9; ++k) mx = fmaxf(mx, lg[k]);
        float e[9]; float s = 0.f;
        #pragma unroll
        for (int k = 0; k < 9; ++k) { e[k] = __expf(lg[k] - mx); s += e[k]; }
        float rinv = 1.f / s;

        int gy = gy0 + ly, gx = gx0 + lx;
        const float* dp = depth + (size_t)b * HH * WW;
        float r = 0.f;
        #pragma unroll
        for (int t = 0; t < 9; ++t) {
            int yy = min(max(gy + t/3 - 1, 0), HH-1);
            int xx = min(max(gx + (t - (t/3)*3) - 1, 0), WW-1);
            r = fmaf(dp[yy*WW + xx], e[t]*rinv, r);
        }
        out[((size_t)b*HH + gy)*WW + gx] = r;
    }
}

extern "C" void kernel_launch(void* const* d_in, const int* in_sizes, int n_in,
                              void* d_out, int out_size, void* d_ws, size_t ws_size,
                              hipStream_t stream) {
    const float* depth = (const float*)d_in[0];
    const float* img   = (const float*)d_in[1];
    const float* w1    = (const float*)d_in[2];
    const float* b1    = (const float*)d_in[3];
    const float* gamma = (const float*)d_in[4];
    const float* beta  = (const float*)d_in[5];
    const float* rmean = (const float*)d_in[6];
    const float* rvar  = (const float*)d_in[7];
    const float* w2    = (const float*)d_in[8];
    float* out = (float*)d_out;

    dim3 grid(WW/TW, HH/TH, 4);
    fastprop_kernel<<<grid, NTHREADS, 0, stream>>>(depth, img, w1, b1, gamma,
                                                   beta, rmean, rvar, w2, out);
}

// Round 2
// 173.331 us; speedup vs baseline: 7.2113x; 7.2113x over previous
//
#include <hip/hip_runtime.h>

#define HH 512
#define WW 640
#define HW (HH*WW)
#define OTW 32
#define OTH 8
#define H1W 36           // padded h1 tile width
#define H1PIXP 384       // 12 groups * 32 (36*10 rounded up)
#define IMW 36
#define IMH 13
#define IMPIX (IMW*IMH)  // 468
#define DTW 34
#define DTH 10
#define NT 256

typedef short short8  __attribute__((ext_vector_type(8)));
typedef short short4v __attribute__((ext_vector_type(4)));
typedef float f32x16  __attribute__((ext_vector_type(16)));
typedef float f32x4   __attribute__((ext_vector_type(4)));

__device__ inline short f2bf(float f) {
    unsigned u = __float_as_uint(f);
    u += 0x7fffu + ((u >> 16) & 1u);   // round-to-nearest-even
    return (short)(u >> 16);
}

__launch_bounds__(NT, 2)
__global__ void fastprop_mfma(const float* __restrict__ depth,
                              const float* __restrict__ img,
                              const float* __restrict__ w1,
                              const float* __restrict__ b1,
                              const float* __restrict__ gamma,
                              const float* __restrict__ beta,
                              const float* __restrict__ rmean,
                              const float* __restrict__ rvar,
                              const float* __restrict__ w2,
                              float* __restrict__ out)
{
    __shared__ short s_img[IMPIX*16];   // [pix][16ch] bf16, 32B/pix
    __shared__ short s_h1 [H1PIXP*40];  // [pix][32ch bf16 + 16B pad], 80B/pix
    __shared__ short s_w1 [9*512];      // [tap][oc32][c16] bf16 (BN-scale folded)
    __shared__ short s_w2 [9*512];      // [tap][f16][c32]  bf16 (f>=9 zero)
    __shared__ float s_depth[DTW*DTH];  // replicate-clamped fp32
    __shared__ float s_bias[32];        // beta + (b1-rmean)*A

    const int tid = threadIdx.x;
    const int bz  = blockIdx.z;
    const int gy0 = blockIdx.y * OTH;
    const int gx0 = blockIdx.x * OTW;
    const float* imgb = img   + (size_t)bz*16*HW;
    const float* dpb  = depth + (size_t)bz*HW;

    // ---------------- stage ----------------
    for (int idx = tid; idx < IMPIX; idx += NT) {
        int iy = idx / IMW, ix = idx - iy*IMW;
        int gy = gy0 + iy - 2, gx = gx0 + ix - 2;
        bool v = ((unsigned)gy < HH) && ((unsigned)gx < WW);
        int cy = min(max(gy, 0), HH-1), cx = min(max(gx, 0), WW-1);
        const float* p = imgb + cy*WW + cx;
        float m = v ? 1.f : 0.f;
        short8 v0, v1;
        #pragma unroll
        for (int c = 0; c < 8; ++c)  v0[c] = f2bf(m * p[c*HW]);
        #pragma unroll
        for (int c = 0; c < 8; ++c)  v1[c] = f2bf(m * p[(c+8)*HW]);
        *(short8*)&s_img[idx*16]     = v0;
        *(short8*)&s_img[idx*16 + 8] = v1;
    }
    for (int i = tid; i < 4608; i += NT) {      // w1: [oc][c][t] -> [t][oc][c], *BN scale
        int oc = i / 144; int rem = i - oc*144; int c = rem / 9; int t = rem - c*9;
        float a = gamma[oc] * rsqrtf(rvar[oc] + 1e-5f);
        s_w1[t*512 + oc*16 + c] = f2bf(w1[i] * a);
    }
    for (int i = tid; i < 4608; i += NT) {      // w2: [f][c][t] -> [t][f16][c32]
        int t = i >> 9, f = (i >> 5) & 15, c = i & 31;
        float val = (f < 9) ? w2[(f*32 + c)*9 + t] : 0.f;
        s_w2[i] = f2bf(val);
    }
    for (int idx = tid; idx < DTW*DTH; idx += NT) {
        int ty = idx / DTW, tx = idx - ty*DTW;
        int gy = min(max(gy0 + ty - 1, 0), HH-1);
        int gx = min(max(gx0 + tx - 1, 0), WW-1);
        s_depth[idx] = dpb[gy*WW + gx];
    }
    if (tid < 32) {
        float a = gamma[tid] * rsqrtf(rvar[tid] + 1e-5f);
        s_bias[tid] = beta[tid] + (b1[tid] - rmean[tid]) * a;
    }
    __syncthreads();

    const int lane = tid & 63;
    const int wid  = tid >> 6;

    // ---------------- conv1 (32x32x16 MFMA, 9 taps) ----------------
    {
        const int oc = lane & 31, cg = lane >> 5;
        short8 a1[9];
        #pragma unroll
        for (int t = 0; t < 9; ++t)
            a1[t] = *(const short8*)&s_w1[t*512 + oc*16 + cg*8];
        float bias_r[16];
        #pragma unroll
        for (int r = 0; r < 16; ++r)
            bias_r[r] = s_bias[(r & 3) + 8*(r >> 2) + 4*cg];

        // tap offsets in shorts: (37 + dy*36 + dx)*16
        const int OFS1[9] = {0, 16, 32, 576, 592, 608, 1152, 1168, 1184};

        for (int g = wid; g < 12; g += 4) {
            int hp   = g*32 + (lane & 31);
            int base = hp*16 + cg*8;
            f32x16 accA, accB;
            #pragma unroll
            for (int i = 0; i < 16; ++i) { accA[i] = 0.f; accB[i] = 0.f; }
            #pragma unroll
            for (int t = 0; t < 9; t += 2)
                accA = __builtin_amdgcn_mfma_f32_32x32x16_bf16(
                         a1[t], *(const short8*)&s_img[base + OFS1[t]], accA, 0, 0, 0);
            #pragma unroll
            for (int t = 1; t < 9; t += 2)
                accB = __builtin_amdgcn_mfma_f32_32x32x16_bf16(
                         a1[t], *(const short8*)&s_img[base + OFS1[t]], accB, 0, 0, 0);
            f32x16 acc = accA + accB;

            unsigned hy = (unsigned)hp / 36u;
            int hx = hp - (int)hy*36;
            int gy = gy0 + (int)hy - 1, gx = gx0 + hx - 1;
            bool inb = ((unsigned)gy < HH) && ((unsigned)gx < WW);
            #pragma unroll
            for (int q = 0; q < 4; ++q) {            // rows 8q + 4cg + 0..3
                short4v h;
                #pragma unroll
                for (int j = 0; j < 4; ++j) {
                    float hv = fmaxf(acc[q*4 + j] + bias_r[q*4 + j], 0.f);
                    h[j] = inb ? f2bf(hv) : (short)0;
                }
                *(short4v*)&s_h1[hp*40 + 8*q + 4*cg] = h;
            }
        }
    }
    __syncthreads();

    // ---------------- conv2 (16x16x32 MFMA, 9 taps) + softmax + gather ----------------
    {
        const int fl = lane & 15, cg2 = lane >> 4;
        short8 a2[9];
        #pragma unroll
        for (int t = 0; t < 9; ++t)
            a2[t] = *(const short8*)&s_w2[t*512 + fl*32 + cg2*8];

        // tap offsets in shorts on s_h1: (dy*36 + dx)*40
        const int OFS2[9] = {-1480, -1440, -1400, -40, 0, 40, 1400, 1440, 1480};

        for (int g = wid; g < 16; g += 4) {
            int po = g*16 + fl;
            int oy = po >> 5, ox = po & 31;
            int hbase = ((oy + 1)*36 + (ox + 1))*40 + cg2*8;
            f32x4 accA, accB;
            #pragma unroll
            for (int i = 0; i < 4; ++i) { accA[i] = 0.f; accB[i] = 0.f; }
            #pragma unroll
            for (int t = 0; t < 9; t += 2)
                accA = __builtin_amdgcn_mfma_f32_16x16x32_bf16(
                         a2[t], *(const short8*)&s_h1[hbase + OFS2[t]], accA, 0, 0, 0);
            #pragma unroll
            for (int t = 1; t < 9; t += 2)
                accB = __builtin_amdgcn_mfma_f32_16x16x32_bf16(
                         a2[t], *(const short8*)&s_h1[hbase + OFS2[t]], accB, 0, 0, 0);
            f32x4 lg = accA + accB;

            float num = 0.f, den = 0.f;
            #pragma unroll
            for (int r = 0; r < 4; ++r) {
                int f = cg2*4 + r;                 // conv2 output channel
                if (f < 9) {
                    float e = __expf(lg[r]);
                    int fy = f/3, fx = f - fy*3;   // tap (dy,dx) = (fy-1, fx-1)
                    float d = s_depth[(oy + fy)*DTW + (ox + fx)];
                    den += e; num += e * d;
                }
            }
            num += __shfl_xor(num, 16); den += __shfl_xor(den, 16);
            num += __shfl_xor(num, 32); den += __shfl_xor(den, 32);
            if (cg2 == 0)
                out[(size_t)bz*HW + (size_t)(gy0 + oy)*WW + (gx0 + ox)] = num / den;
        }
    }
}

extern "C" void kernel_launch(void* const* d_in, const int* in_sizes, int n_in,
                              void* d_out, int out_size, void* d_ws, size_t ws_size,
                              hipStream_t stream) {
    const float* depth = (const float*)d_in[0];
    const float* img   = (const float*)d_in[1];
    const float* w1    = (const float*)d_in[2];
    const float* b1    = (const float*)d_in[3];
    const float* gamma = (const float*)d_in[4];
    const float* beta  = (const float*)d_in[5];
    const float* rmean = (const float*)d_in[6];
    const float* rvar  = (const float*)d_in[7];
    const float* w2    = (const float*)d_in[8];
    float* out = (float*)d_out;

    dim3 grid(WW/OTW, HH/OTH, 4);
    fastprop_mfma<<<grid, NT, 0, stream>>>(depth, img, w1, b1, gamma,
                                           beta, rmean, rvar, w2, out);
}

// Round 3
// 64.477 us; speedup vs baseline: 19.3859x; 2.6883x over previous
//
#include <hip/hip_runtime.h>
#include <hip/hip_bf16.h>

#define HH 512
#define WW 640
#define HW (HH*WW)
#define NT 256

typedef short short8  __attribute__((ext_vector_type(8)));
typedef short short4v __attribute__((ext_vector_type(4)));
typedef float f32x16  __attribute__((ext_vector_type(16)));
typedef float f32x4   __attribute__((ext_vector_type(4)));

__device__ inline short f2bf(float f) {
    __hip_bfloat16 h = __float2bfloat16(f);
    short s; __builtin_memcpy(&s, &h, 2);
    return s;
}

// ---------------- prep: fold BN into w1, transpose weights to MFMA layouts ----------------
__global__ void prep_weights(const float* __restrict__ w1, const float* __restrict__ b1,
                             const float* __restrict__ gamma, const float* __restrict__ beta,
                             const float* __restrict__ rmean, const float* __restrict__ rvar,
                             const float* __restrict__ w2,
                             short* __restrict__ ws_w1, short* __restrict__ ws_w2,
                             float* __restrict__ ws_bias)
{
    int tid = blockIdx.x*blockDim.x + threadIdx.x;
    int stride = gridDim.x*blockDim.x;
    for (int i = tid; i < 4608; i += stride) {          // w1: [oc][c][t] -> [t][oc32][c16] * A_oc
        int oc = i / 144, rem = i - oc*144, c = rem / 9, t = rem - c*9;
        float a = gamma[oc] * rsqrtf(rvar[oc] + 1e-5f);
        ws_w1[t*512 + oc*16 + c] = f2bf(w1[i] * a);
    }
    for (int i = tid; i < 4608; i += stride) {          // w2: [f][c][t] -> [t][f16][c32], f>=9 zero
        int t = i >> 9, f = (i >> 5) & 15, c = i & 31;
        float val = (f < 9) ? w2[(f*32 + c)*9 + t] : 0.f;
        ws_w2[i] = f2bf(val);
    }
    if (tid < 32) {
        float a = gamma[tid] * rsqrtf(rvar[tid] + 1e-5f);
        ws_bias[tid] = beta[tid] + (b1[tid] - rmean[tid]) * a;
    }
}

// ---------------- main fused kernel ----------------
__launch_bounds__(NT, 4)
__global__ void fastprop_main(const float* __restrict__ depth,
                              const float* __restrict__ img,
                              const short* __restrict__ ws_w1,
                              const short* __restrict__ ws_w2,
                              const float* __restrict__ ws_bias,
                              float* __restrict__ out)
{
    __shared__ short s_img[468*16];   // [pix36x13][16ch] bf16, 32B/pix (14976 B)
    __shared__ short s_h1 [360*32];   // [pix36x10][32ch] bf16, 64B/pix (23040 B)
    __shared__ float s_depth[340];    // 34x10 replicate-clamped fp32 (1360 B)

    const int tid = threadIdx.x;

    // XCD-contiguous bijective remap: 5120 blocks = 8 XCDs x 640
    int nid = blockIdx.x;
    int oid = (nid & 7)*640 + (nid >> 3);
    int bz = oid / 1280; int rem = oid - bz*1280;
    int by = rem / 20;   int bx = rem - by*20;
    const int gy0 = by*8, gx0 = bx*32;

    const float* imgb = img   + (size_t)bz*16*HW;
    const float* dpb  = depth + (size_t)bz*HW;

    const int lane = tid & 63;
    const int wid  = tid >> 6;

    // conv1 A-fragments + bias from ws (L2-resident, per-lane b128 loads)
    const int oc = lane & 31, cg = lane >> 5;
    short8 a1[9];
    #pragma unroll
    for (int t = 0; t < 9; ++t)
        a1[t] = *(const short8*)&ws_w1[t*512 + oc*16 + cg*8];
    float bias_r[16];
    #pragma unroll
    for (int r = 0; r < 16; ++r)
        bias_r[r] = ws_bias[(r & 3) + 8*(r >> 2) + 4*cg];

    // ---- stage img tile (36x13 halo, zero at image OOB) + depth tile ----
    for (int idx = tid; idx < 468; idx += NT) {
        int iy = idx / 36, ix = idx - iy*36;
        int gy = gy0 + iy - 2, gx = gx0 + ix - 2;
        bool v = ((unsigned)gy < HH) && ((unsigned)gx < WW);
        int cy = min(max(gy, 0), HH-1), cx = min(max(gx, 0), WW-1);
        const float* p = imgb + cy*WW + cx;
        float m = v ? 1.f : 0.f;
        short8 v0, v1;
        #pragma unroll
        for (int c = 0; c < 8; ++c)  v0[c] = f2bf(m * p[c*HW]);
        #pragma unroll
        for (int c = 0; c < 8; ++c)  v1[c] = f2bf(m * p[(c+8)*HW]);
        *(short8*)&s_img[idx*16]     = v0;
        *(short8*)&s_img[idx*16 + 8] = v1;
    }
    for (int idx = tid; idx < 340; idx += NT) {
        int ty = idx / 34, tx = idx - ty*34;
        int gy = min(max(gy0 + ty - 1, 0), HH-1);
        int gx = min(max(gx0 + tx - 1, 0), WW-1);
        s_depth[idx] = dpb[gy*WW + gx];
    }
    __syncthreads();

    // ---- conv1 (32x32x16 MFMA, 9 taps) -> s_h1 ----
    {
        // tap pixel deltas on img tile: (dy+1)*36 + (dx+1), in shorts (*16)
        const int OFS1[9] = {0, 16, 32, 576, 592, 608, 1152, 1168, 1184};

        for (int g = wid; g < 12; g += 4) {
            int hp   = g*32 + (lane & 31);
            int base = hp*16 + cg*8;
            f32x16 accA, accB;
            #pragma unroll
            for (int i = 0; i < 16; ++i) { accA[i] = 0.f; accB[i] = 0.f; }
            #pragma unroll
            for (int t = 0; t < 9; t += 2)
                accA = __builtin_amdgcn_mfma_f32_32x32x16_bf16(
                         a1[t], *(const short8*)&s_img[base + OFS1[t]], accA, 0, 0, 0);
            #pragma unroll
            for (int t = 1; t < 9; t += 2)
                accB = __builtin_amdgcn_mfma_f32_32x32x16_bf16(
                         a1[t], *(const short8*)&s_img[base + OFS1[t]], accB, 0, 0, 0);
            f32x16 acc = accA + accB;

            if (hp < 360) {
                unsigned hy = (unsigned)hp / 36u;
                int hx = hp - (int)hy*36;
                int gy = gy0 + (int)hy - 1, gx = gx0 + hx - 1;
                bool inb = ((unsigned)gy < HH) && ((unsigned)gx < WW);
                #pragma unroll
                for (int q = 0; q < 4; ++q) {            // channels 8q + 4cg + 0..3
                    short4v h;
                    #pragma unroll
                    for (int j = 0; j < 4; ++j) {
                        float hv = fmaxf(acc[q*4 + j] + bias_r[q*4 + j], 0.f);
                        h[j] = inb ? f2bf(hv) : (short)0;
                    }
                    *(short4v*)&s_h1[hp*32 + 8*q + 4*cg] = h;
                }
            }
        }
    }
    __syncthreads();

    // ---- conv2 (16x16x32 MFMA, 9 taps) + softmax + depth gather ----
    {
        const int fl = lane & 15, cg2 = lane >> 4;
        short8 a2[9];
        #pragma unroll
        for (int t = 0; t < 9; ++t)
            a2[t] = *(const short8*)&ws_w2[t*512 + fl*32 + cg2*8];

        // tap pixel deltas on h1 tile: dy*36 + dx, in shorts (*32)
        const int OFS2[9] = {-1184, -1152, -1120, -32, 0, 32, 1120, 1152, 1184};

        for (int g = wid; g < 16; g += 4) {
            int po = g*16 + fl;
            int oy = po >> 5, ox = po & 31;
            int hbase = ((oy + 1)*36 + (ox + 1))*32 + cg2*8;
            f32x4 accA, accB;
            #pragma unroll
            for (int i = 0; i < 4; ++i) { accA[i] = 0.f; accB[i] = 0.f; }
            #pragma unroll
            for (int t = 0; t < 9; t += 2)
                accA = __builtin_amdgcn_mfma_f32_16x16x32_bf16(
                         a2[t], *(const short8*)&s_h1[hbase + OFS2[t]], accA, 0, 0, 0);
            #pragma unroll
            for (int t = 1; t < 9; t += 2)
                accB = __builtin_amdgcn_mfma_f32_16x16x32_bf16(
                         a2[t], *(const short8*)&s_h1[hbase + OFS2[t]], accB, 0, 0, 0);
            f32x4 lg = accA + accB;

            float num = 0.f, den = 0.f;
            #pragma unroll
            for (int r = 0; r < 4; ++r) {
                int f = cg2*4 + r;                 // conv2 output channel
                if (f < 9) {
                    float e = __expf(lg[r]);
                    int fy = f/3, fx = f - fy*3;   // tap (dy,dx) = (fy-1, fx-1)
                    float d = s_depth[(oy + fy)*34 + (ox + fx)];
                    den += e; num += e * d;
                }
            }
            num += __shfl_xor(num, 16); den += __shfl_xor(den, 16);
            num += __shfl_xor(num, 32); den += __shfl_xor(den, 32);
            if (cg2 == 0)
                out[(size_t)bz*HW + (size_t)(gy0 + oy)*WW + (gx0 + ox)] = num / den;
        }
    }
}

extern "C" void kernel_launch(void* const* d_in, const int* in_sizes, int n_in,
                              void* d_out, int out_size, void* d_ws, size_t ws_size,
                              hipStream_t stream) {
    const float* depth = (const float*)d_in[0];
    const float* img   = (const float*)d_in[1];
    const float* w1    = (const float*)d_in[2];
    const float* b1    = (const float*)d_in[3];
    const float* gamma = (const float*)d_in[4];
    const float* beta  = (const float*)d_in[5];
    const float* rmean = (const float*)d_in[6];
    const float* rvar  = (const float*)d_in[7];
    const float* w2    = (const float*)d_in[8];
    float* out = (float*)d_out;

    short* ws_w1   = (short*)d_ws;                       // 4608 shorts
    short* ws_w2   = ws_w1 + 4608;                       // 4608 shorts
    float* ws_bias = (float*)((char*)d_ws + 36864);      // 32 floats

    prep_weights<<<16, NT, 0, stream>>>(w1, b1, gamma, beta, rmean, rvar, w2,
                                        ws_w1, ws_w2, ws_bias);
    fastprop_main<<<5120, NT, 0, stream>>>(depth, img, ws_w1, ws_w2, ws_bias, out);
}